// Round 2
// baseline (959.716 us; speedup 1.0000x reference)
//
#include <hip/hip_runtime.h>
#include <stdint.h>

// TT-stack: out[b][(a,c,d)][(i,j,l)] = sum_{k,m} c0[s][a,i,k] c1[s][k,c,j,m] c2[s][m,d,l]
// One block per b (512 blocks x 512 threads). c1 staged ONCE per b.
// Step1 (VALU): t[c,i,j][m] fp32 -> bf16 in LDS, wave-private rows (c = wave id),
// barrier-free a-loop. Step2 on MFMA 16x16x32_bf16 with SWAPPED operands:
//   A = c2 rows=(d,l), kk=32 (hi bf16 | lo bf16 of fp32 c2 folded into K axis)
//   B = t  cols=(c,i,j), m duplicated over both K halves
// => D rows=(d,l): each lane's 4 regs = 4 consecutive l -> contiguous float4
// stores; a wave store covers two 512B fully-aligned segments (whole L2 lines),
// eliminating the R1 write-allocate RMW (FETCH was ~output-sized).

typedef short short8 __attribute__((ext_vector_type(8)));
typedef float f32x4 __attribute__((ext_vector_type(4)));

__device__ __forceinline__ float bflo(uint32_t u) { return __uint_as_float(u << 16); }
__device__ __forceinline__ float bfhi(uint32_t u) { return __uint_as_float(u & 0xffff0000u); }
__device__ __forceinline__ uint32_t pack_bf2(float f0, float f1) {
  uint32_t a = __float_as_uint(f0) + 0x8000u;
  uint32_t b = __float_as_uint(f1) + 0x8000u;
  return (a >> 16) | (b & 0xffff0000u);
}

__global__ __launch_bounds__(512, 4) void tt_stack_kernel(
    const float* __restrict__ c0f,
    const float* __restrict__ c1f,
    const float* __restrict__ c2f,
    const int* __restrict__ idx,
    float* __restrict__ outf)
{
  __shared__ __align__(16) uint32_t lds_c1[8192];   // bf16 pairs [k][c][j][m/2]  32 KB
  __shared__ __align__(16) float    lds_c0[1024];   // fp32 [a][i][k]              4 KB
  __shared__ __align__(16) uint32_t lds_c2b[1024];  // bf16 [row=(d,l)][kk=32]     4 KB
  __shared__ __align__(16) uint32_t lds_t[4096];    // bf16 [row=512][m=16] swz   16 KB

  const int tid = threadIdx.x;
  const int b = blockIdx.x;
  const int s = idx[b];
  const size_t s1024 = (size_t)s * 1024;

  // ---- stage: c1 (coalesced float4 -> bf16 pairs), c0 fp32, c2 -> hi/lo bf16 ----
  {
    const float4* src4 = (const float4*)(c1f + (size_t)s * 16384);
    float4 cv[8];
#pragma unroll
    for (int it = 0; it < 8; ++it) cv[it] = src4[it * 512 + tid];
    const float g0 = c0f[s1024 + tid];
    const float g1 = c0f[s1024 + 512 + tid];
    const int w = tid & 7;        // m-pair index (m = 2w, 2w+1)
    const int col = tid >> 3;     // (d,l) row 0..63
    const float v0 = c2f[s1024 + (size_t)(2 * w) * 64 + col];
    const float v1 = c2f[s1024 + (size_t)(2 * w + 1) * 64 + col];
#pragma unroll
    for (int it = 0; it < 8; ++it) {
      uint2* dst = (uint2*)&lds_c1[2 * (it * 512 + tid)];
      *dst = make_uint2(pack_bf2(cv[it].x, cv[it].y), pack_bf2(cv[it].z, cv[it].w));
    }
    lds_c0[tid] = g0;
    lds_c0[512 + tid] = g1;
    // c2 hi = bf16(v) in kk 0..15 (words 0..7), lo = bf16(v-hi) in kk 16..31.
    const uint32_t h0 = (__float_as_uint(v0) + 0x8000u) & 0xffff0000u;
    const uint32_t h1 = (__float_as_uint(v1) + 0x8000u) & 0xffff0000u;
    lds_c2b[col * 16 + w] = (h0 >> 16) | h1;
    lds_c2b[col * 16 + 8 + w] =
        pack_bf2(v0 - __uint_as_float(h0), v1 - __uint_as_float(h1));
  }
  __syncthreads();  // the only barrier

  const int lane = tid & 63, wv = tid >> 6;
  const int g = lane >> 4, lcol = lane & 15;

  // A-fragments: c2 over kk=32, A row=(d,l)=rt*16+lcol, k=g*8+e. a-invariant.
  short8 Afr[4];
#pragma unroll
  for (int rt = 0; rt < 4; ++rt)
    Afr[rt] = *(const short8*)&lds_c2b[(rt * 16 + lcol) * 16 + g * 4];

  const int c = wv, i = (tid >> 3) & 7, j = tid & 7;   // step1 row = tid
  const int sw = (tid >> 2) & 1;                 // t-row half swizzle (write side)
  const int hsel = (g & 1) ^ ((lcol >> 2) & 1);  // t-row half swizzle (read side)
  float* const outb = outf + (size_t)b * 262144;
  // store base: row (c*8 + rt*2 + (g>>1)), col (ct*2+(lcol>>3))*64+(lcol&7)*8+(g&1)*4
  float* const obase = outb + c * 4096 + (g >> 1) * 512
                            + (lcol >> 3) * 64 + (lcol & 7) * 8 + (g & 1) * 4;

  for (int a = 0; a < 8; ++a) {
    // ---- step 1: t[row=(c,i,j)][m] = sum_k c0[a,i,k] * c1[k,c,j,m]  (VALU) ----
    float a_k[16];
    {
      const float4* c0p = (const float4*)&lds_c0[a * 128 + i * 16];
#pragma unroll
      for (int q = 0; q < 4; ++q) *(float4*)&a_k[q * 4] = c0p[q];
    }
    float acc[16];
#pragma unroll
    for (int m = 0; m < 16; ++m) acc[m] = 0.f;
#pragma unroll
    for (int k = 0; k < 16; ++k) {
      const uint4* rp = (const uint4*)&lds_c1[((k * 8 + c) * 8 + j) * 8];
      const uint4 u0 = rp[0];
      const uint4 u1 = rp[1];
      const float av = a_k[k];
      acc[0]  = fmaf(av, bflo(u0.x), acc[0]);   acc[1]  = fmaf(av, bfhi(u0.x), acc[1]);
      acc[2]  = fmaf(av, bflo(u0.y), acc[2]);   acc[3]  = fmaf(av, bfhi(u0.y), acc[3]);
      acc[4]  = fmaf(av, bflo(u0.z), acc[4]);   acc[5]  = fmaf(av, bfhi(u0.z), acc[5]);
      acc[6]  = fmaf(av, bflo(u0.w), acc[6]);   acc[7]  = fmaf(av, bfhi(u0.w), acc[7]);
      acc[8]  = fmaf(av, bflo(u1.x), acc[8]);   acc[9]  = fmaf(av, bfhi(u1.x), acc[9]);
      acc[10] = fmaf(av, bflo(u1.y), acc[10]);  acc[11] = fmaf(av, bfhi(u1.y), acc[11]);
      acc[12] = fmaf(av, bflo(u1.z), acc[12]);  acc[13] = fmaf(av, bfhi(u1.z), acc[13]);
      acc[14] = fmaf(av, bflo(u1.w), acc[14]);  acc[15] = fmaf(av, bfhi(u1.w), acc[15]);
    }
    // write own t row (wave-private region), halves XOR-swizzled by (row>>2)&1
    {
      uint32_t* tb = &lds_t[tid * 8];
      *(uint4*)&tb[sw * 4] =
          make_uint4(pack_bf2(acc[0], acc[1]),  pack_bf2(acc[2], acc[3]),
                     pack_bf2(acc[4], acc[5]),  pack_bf2(acc[6], acc[7]));
      *(uint4*)&tb[4 - sw * 4] =
          make_uint4(pack_bf2(acc[8], acc[9]),  pack_bf2(acc[10], acc[11]),
                     pack_bf2(acc[12], acc[13]), pack_bf2(acc[14], acc[15]));
    }

    // ---- step 2: D[(d,l)][(i,j)] = c2 @ t  via mfma(A=c2, B=t) ----
    // B lane(col=lcol) reads m-half (g&1) of t row wv*64+ct*16+lcol (own wave's rows).
    float* const oa = obase + a * 32768;
#pragma unroll
    for (int ct = 0; ct < 4; ++ct) {
      const short8 bv8 =
          *(const short8*)&lds_t[(wv * 64 + ct * 16 + lcol) * 8 + hsel * 4];
      float* const oc = oa + ct * 128;
#pragma unroll
      for (int rt = 0; rt < 4; ++rt) {
        f32x4 dd = {0.f, 0.f, 0.f, 0.f};
        dd = __builtin_amdgcn_mfma_f32_16x16x32_bf16(Afr[rt], bv8, dd, 0, 0, 0);
        // D: col=lane&15 -> (i,j); row=(lane>>4)*4+reg -> (d, l0+reg) contiguous
        *(float4*)(oc + rt * 1024) = make_float4(dd[0], dd[1], dd[2], dd[3]);
      }
    }
    // next a: same wave overwrites its own t rows -> DS in-order, no barrier
  }
}

extern "C" void kernel_launch(void* const* d_in, const int* in_sizes, int n_in,
                              void* d_out, int out_size, void* d_ws, size_t ws_size,
                              hipStream_t stream) {
  const float* c0f = (const float*)d_in[0];
  const float* c1f = (const float*)d_in[1];
  const float* c2f = (const float*)d_in[2];
  const int* idx = (const int*)d_in[3];
  float* outf = (float*)d_out;
  const int B = in_sizes[3];  // 512
  dim3 grid(B), block(512);
  hipLaunchKernelGGL(tt_stack_kernel, grid, block, 0, stream, c0f, c1f, c2f, idx, outf);
}

// Round 4
// 581.006 us; speedup vs baseline: 1.6518x; 1.6518x over previous
//
#include <hip/hip_runtime.h>
#include <stdint.h>

// TT-stack: out[b][(a,c,d)][(i,j,l)] = sum_{k,m} c0[s][a,i,k] c1[s][k,c,j,m] c2[s][m,d,l]
// R0 skeleton (proven 263us kernel): block = one (b,a), 4096 blocks x 256 threads,
// 3 blocks/CU. Step1 unchanged (VALU, fp32 c0 x bf16 c1 -> t).
// Step2 replaced by MFMA 16x16x32_bf16 (R2-validated fragment construction):
//   A = c2 rows=(d,l), K=32 = (hi bf16 | lo bf16) of fp32 c2
//   B = t  cols=(c,i,j), m duplicated over both K halves via half-swap swizzle
//   D: col=lane&15 -> (c,i,j); row=(lane>>4)*4+reg -> (d, l0+reg) => contiguous
//   float4 stores, 2x512B dense aligned segments per wave-instruction.
// Output stores are NONTEMPORAL (write-once stream; tests write-allocate theory).
// [R4 = R3 resubmit: R3 bench was an infra failure, kernel never ran.]

typedef short short8 __attribute__((ext_vector_type(8)));
typedef float f32x4 __attribute__((ext_vector_type(4)));

__device__ __forceinline__ float bflo(uint32_t u) { return __uint_as_float(u << 16); }
__device__ __forceinline__ float bfhi(uint32_t u) { return __uint_as_float(u & 0xffff0000u); }
__device__ __forceinline__ uint32_t pack_bf2(float f0, float f1) {
  uint32_t a = __float_as_uint(f0) + 0x8000u;
  uint32_t b = __float_as_uint(f1) + 0x8000u;
  return (a >> 16) | (b & 0xffff0000u);
}

__global__ __launch_bounds__(256) void tt_stack_kernel(
    const float* __restrict__ c0f,
    const float* __restrict__ c1f,
    const float* __restrict__ c2f,
    const int* __restrict__ idx,
    float* __restrict__ outf)
{
  __shared__ __align__(16) uint32_t lds_c1[8192];   // bf16 pairs [k][c][j][m/2] 32 KB
  __shared__ __align__(16) float    lds_c0[128];    // fp32 [i][k]               0.5 KB
  __shared__ __align__(16) uint32_t lds_c2b[1024];  // bf16 [row=(d,l)][kk=32]   4 KB
  __shared__ __align__(16) uint32_t lds_t[4096];    // bf16 [row=512][m=16] swz  16 KB

  const int tid = threadIdx.x;
  const int bid = blockIdx.x;
  const int b = bid >> 3;
  const int a = bid & 7;
  const int s = idx[b];
  const size_t s1024 = (size_t)s * 1024;

  // ---- stage c1: fp32 global -> bf16 pairs in LDS, coalesced float4 (R0) ----
  {
    const float4* src4 = (const float4*)(c1f + (size_t)s * 16384);
#pragma unroll
    for (int r = 0; r < 16; ++r) {
      const float4 v = src4[r * 256 + tid];
      uint2* dst = (uint2*)&lds_c1[2 * (r * 256 + tid)];
      *dst = make_uint2(pack_bf2(v.x, v.y), pack_bf2(v.z, v.w));
    }
  }
  // ---- c0 row for this a, fp32 ----
  if (tid < 128) lds_c0[tid] = c0f[(size_t)(s * 8 + a) * 128 + tid];
  // ---- c2 -> hi/lo bf16 over K=32: words 0..7 = hi(m0..15), 8..15 = lo ----
#pragma unroll
  for (int rep = 0; rep < 2; ++rep) {
    const int t2 = tid + rep * 256;
    const int w = t2 & 7;        // m-pair (m = 2w, 2w+1)
    const int col = t2 >> 3;     // (d,l) row 0..63
    const float v0 = c2f[s1024 + (size_t)(2 * w) * 64 + col];
    const float v1 = c2f[s1024 + (size_t)(2 * w + 1) * 64 + col];
    const uint32_t h0 = (__float_as_uint(v0) + 0x8000u) & 0xffff0000u;
    const uint32_t h1 = (__float_as_uint(v1) + 0x8000u) & 0xffff0000u;
    lds_c2b[col * 16 + w] = (h0 >> 16) | h1;
    lds_c2b[col * 16 + 8 + w] =
        pack_bf2(v0 - __uint_as_float(h0), v1 - __uint_as_float(h1));
  }
  __syncthreads();

  // ---- step 1 (R0): t[c,i,j][m] = sum_k c0[i,k] * c1[k,c,j,m]; 2 rows/thread ----
  const int sw = (tid >> 2) & 1;  // t half-swap swizzle key (row bit 2)
#pragma unroll
  for (int cc = 0; cc < 2; ++cc) {
    const int combo = tid + cc * 256;      // row (c,i,j)
    const int c = combo >> 6;
    const int i = (combo >> 3) & 7;
    const int j = combo & 7;
    float a_k[16];
#pragma unroll
    for (int k = 0; k < 16; ++k) a_k[k] = lds_c0[i * 16 + k];
    float acc[16];
#pragma unroll
    for (int m = 0; m < 16; ++m) acc[m] = 0.f;
#pragma unroll
    for (int k = 0; k < 16; ++k) {
      const uint4* rp = (const uint4*)&lds_c1[((k * 8 + c) * 8 + j) * 8];
      const uint4 u0 = rp[0];
      const uint4 u1 = rp[1];
      const float av = a_k[k];
      acc[0]  = fmaf(av, bflo(u0.x), acc[0]);   acc[1]  = fmaf(av, bfhi(u0.x), acc[1]);
      acc[2]  = fmaf(av, bflo(u0.y), acc[2]);   acc[3]  = fmaf(av, bfhi(u0.y), acc[3]);
      acc[4]  = fmaf(av, bflo(u0.z), acc[4]);   acc[5]  = fmaf(av, bfhi(u0.z), acc[5]);
      acc[6]  = fmaf(av, bflo(u0.w), acc[6]);   acc[7]  = fmaf(av, bfhi(u0.w), acc[7]);
      acc[8]  = fmaf(av, bflo(u1.x), acc[8]);   acc[9]  = fmaf(av, bfhi(u1.x), acc[9]);
      acc[10] = fmaf(av, bflo(u1.y), acc[10]);  acc[11] = fmaf(av, bfhi(u1.y), acc[11]);
      acc[12] = fmaf(av, bflo(u1.z), acc[12]);  acc[13] = fmaf(av, bfhi(u1.z), acc[13]);
      acc[14] = fmaf(av, bflo(u1.w), acc[14]);  acc[15] = fmaf(av, bfhi(u1.w), acc[15]);
    }
    // write t row; m-halves swapped when (row>>2)&1 == 1 (read side undoes it)
    uint32_t* tb = &lds_t[combo * 8];
    *(uint4*)&tb[sw * 4] =
        make_uint4(pack_bf2(acc[0], acc[1]),  pack_bf2(acc[2], acc[3]),
                   pack_bf2(acc[4], acc[5]),  pack_bf2(acc[6], acc[7]));
    *(uint4*)&tb[4 - sw * 4] =
        make_uint4(pack_bf2(acc[8], acc[9]),  pack_bf2(acc[10], acc[11]),
                   pack_bf2(acc[12], acc[13]), pack_bf2(acc[14], acc[15]));
  }
  __syncthreads();

  // ---- step 2: D[(d,l)][(c,i,j)] = c2 @ t via mfma(A=c2, B=t) ----
  const int lane = tid & 63, wv = tid >> 6;
  const int g = lane >> 4, lcol = lane & 15;
  short8 Afr[4];
#pragma unroll
  for (int rt = 0; rt < 4; ++rt)
    Afr[rt] = *(const short8*)&lds_c2b[(rt * 16 + lcol) * 16 + g * 4];
  const int hsel = (g & 1) ^ ((lcol >> 2) & 1);
  float* const outa = outf + (size_t)b * 262144 + a * 32768;

#pragma unroll
  for (int ctl = 0; ctl < 8; ++ctl) {
    const int cix = wv * 128 + ctl * 16 + lcol;   // B col = (c,i,j)
    const short8 bv8 = *(const short8*)&lds_t[cix * 8 + hsel * 4];
    const int cq = cix >> 6;      // c
    const int klo = cix & 63;     // (i, j)
    // row = cq*8 + d, d = rt*2 + (g>>1); col floats = klo*8 + (g&1)*4 + reg
    float* const op0 = outa + (size_t)(cq * 8 + (g >> 1)) * 512
                            + klo * 8 + (g & 1) * 4;
#pragma unroll
    for (int rt = 0; rt < 4; ++rt) {
      f32x4 dd = {0.f, 0.f, 0.f, 0.f};
      dd = __builtin_amdgcn_mfma_f32_16x16x32_bf16(Afr[rt], bv8, dd, 0, 0, 0);
      __builtin_nontemporal_store(dd, (f32x4*)(op0 + rt * 1024));
    }
  }
}

extern "C" void kernel_launch(void* const* d_in, const int* in_sizes, int n_in,
                              void* d_out, int out_size, void* d_ws, size_t ws_size,
                              hipStream_t stream) {
  const float* c0f = (const float*)d_in[0];
  const float* c1f = (const float*)d_in[1];
  const float* c2f = (const float*)d_in[2];
  const int* idx = (const int*)d_in[3];
  float* outf = (float*)d_out;
  const int B = in_sizes[3];  // 512
  dim3 grid(B * 8), block(256);
  hipLaunchKernelGGL(tt_stack_kernel, grid, block, 0, stream, c0f, c1f, c2f, idx, outf);
}